// Round 5
// baseline (173.487 us; speedup 1.0000x reference)
//
#include <hip/hip_runtime.h>

// NCC loss, win=9, (1,1,160,192,224) fp32 -> scalar. Fully fused, round 14.
// R9-R13 post-mortem: dur ~58-66us invariant to barriers/balance/occupancy;
// VALU stuck 35-40%. Arithmetic: R12 moved 30.7KB LDS per block-slice; at
// ~112 B/cyc/CU with 4 resident blocks = ~1100 cyc/phase/CU, matching the
// measured ~965-cyc phase budget -> LDS-BANDWIDTH BOUND. R13 (+LDS) regressed,
// confirming.
// R14: delete the SW buffer and H stage entirely. W-stage remapped so each
// 16-row column lives in 16 consecutive lanes of one wave (row = lane&15);
// the vertical 9-tap H-sum becomes a pure-VALU DPP row_shr scan (16-lane row
// domain == our column):
//   s1=v+sr1(v); s2=s1+sr2(s1); s4=s2+sr4(s2); s9=s4+sr8(v)   (4 fused ops)
// Out-row c lands at lane c+8; lanes with bit3 set store float4 H-sums to SH.
// LDS per block-slice: 30.7KB -> 10.2KB (3x cut of the saturated resource).
// Pipeline: 2 stages, SH double-buffered, ONE LDS-only barrier per phase:
//   bar; { F(j): SH[j&1] -> ring/cc  ||  WH(j+1): pf regs -> SH[(j+1)&1];
//          w_load(j+2) }
// All 4 waves run W: lane<32 -> ch {I, J, I*I}; lane>=32 -> ch {J*J, I*J}.
// SH channel stride 292 (=8*36+4) kills the sub0/sub1 store-bank overlap.
// DCH=28, 1008 blocks, 256 threads (1 output/thread keeps D-ring in regs).

#define DD 160
#define HH 192
#define WW 224
#define W4 56                 // WW/4
#define SLICE (HH * WW)
#define S4 (SLICE / 4)
#define NVOX (DD * SLICE)
#define TW 32
#define TH 8
#define DCH 28                // grid.z = 6 -> 1008 blocks
#define ITERS (DCH + 8)       // 36 = 4 * 9 (phase-static ring)
#define NTHR 256
#define SH_RS 36              // row stride (dwords): 2-way max on F reads
#define SH_CS 292             // channel stride: 8*36+4 -> de-aliases W stores
#define SH_SZ (5 * SH_CS)     // 1460 floats = 5.84 KB per buffer
#define EPS 1e-5f
#define INV_WSUM (1.0f / 729.0f)

// Barrier that orders LDS only: s_waitcnt imm 0xC07F = lgkmcnt(0), vmcnt(63),
// expcnt(7) -> in-flight GLOBAL loads stay in flight across the barrier.
__device__ __forceinline__ void bar_lds_only() {
    __asm__ volatile("" ::: "memory");
    __builtin_amdgcn_s_waitcnt(0xC07F);
    __builtin_amdgcn_s_barrier();
    __asm__ volatile("" ::: "memory");
}

// acc + (x shifted down by N lanes within each 16-lane DPP row, zero-fill).
template <int N>
__device__ __forceinline__ float sr_add(float acc, float x) {
    int sh = __builtin_amdgcn_update_dpp(0, __float_as_int(x),
                                         0x110 | N, 0xF, 0xF, true);
    return acc + __int_as_float(sh);
}

// 9-tap window sum ending at this lane, across the 16-lane row: lane l gets
// sum of lanes l-8..l (zeros below lane 0 of the row).
__device__ __forceinline__ float vert9(float v) {
    float s1 = sr_add<1>(v, v);    // 2-tap
    float s2 = sr_add<2>(s1, s1);  // 4-tap
    float s4 = sr_add<4>(s2, s2);  // 8-tap (l-7..l)
    return sr_add<8>(s4, v);       // + v[l-8] -> 9-tap
}

__global__ __launch_bounds__(NTHR, 4) void ncc_fused(const float* __restrict__ I,
                                                     const float* __restrict__ J,
                                                     float* __restrict__ out) {
    __shared__ float SH0[SH_SZ], SH1[SH_SZ];   // 5.84 KB each
    __shared__ float wred[NTHR / 64];

    const int tid = threadIdx.x;
    const int wlo = blockIdx.x * TW;
    const int hlo = blockIdx.y * TH;
    const int dlo = blockIdx.z * DCH;

    // W/H mapping: wave wv, lane: 16-lane rows = columns of the tile.
    const int lane = tid & 63;
    const int wv   = tid >> 6;
    const int sub  = lane >> 5;              // 0: ch I,J,I*I ; 1: ch J*J,I*J
    const int r16  = lane & 15;              // tile row - 4 .. +11
    const int g    = 2 * wv + ((lane >> 4) & 1);   // f4 col-group 0..7
    const int gh   = hlo - 4 + r16;
    const bool hok = (gh >= 0) && (gh < HH);
    const int gf0  = (wlo >> 2) - 1 + g;
    const bool wrt = ((lane >> 3) & 1) != 0; // lanes r16 in 8..15 hold outputs
    const int crow = lane & 7;               // out row 0..7 (writers only)

    // F mapping: 32 x 8, one output voxel per thread
    const int fx = tid & 31, fy = tid >> 5;

    const float4* Iv = (const float4*)I;
    const float4* Jv = (const float4*)J;

    // prefetch registers: 3 f4 taps of raw I/J for this lane's (row, group)
    float pfa[12], pfb[12];

    auto w_load = [&](int z) {   // fill pfa/pfb for slice z (zeros if OOB)
        const bool zok = (z >= 0) && (z < DD) && hok;
        const int rowb = z * S4 + gh * W4;
        #pragma unroll
        for (int k = 0; k < 3; ++k) {
            const int f = gf0 + k;
            float4 a = make_float4(0.f, 0.f, 0.f, 0.f);
            float4 b = make_float4(0.f, 0.f, 0.f, 0.f);
            if (zok && f >= 0 && f < W4) { a = Iv[rowb + f]; b = Jv[rowb + f]; }
            pfa[4*k] = a.x; pfa[4*k+1] = a.y; pfa[4*k+2] = a.z; pfa[4*k+3] = a.w;
            pfb[4*k] = b.x; pfb[4*k+1] = b.y; pfb[4*k+2] = b.z; pfb[4*k+3] = b.w;
        }
    };

    // W-slide (horizontal 9-tap) + DPP vertical 9-tap + SH store.
    auto wh_phase = [&](float* shDst) {
        #pragma unroll
        for (int t = 0; t < 3; ++t) {
            if (t == 2 && sub) continue;   // sub1 has only 2 channels; DPP rows
                                           // of sub0 stay fully active
            float v[12];
            #pragma unroll
            for (int k = 0; k < 12; ++k)
                v[k] = (t == 0) ? (sub ? pfb[k] * pfb[k] : pfa[k])
                     : (t == 1) ? (sub ? pfa[k] * pfb[k] : pfb[k])
                     :            pfa[k] * pfa[k];
            float s = v[0];
            #pragma unroll
            for (int k = 1; k < 9; ++k) s += v[k];
            float4 o;
            o.x = s;
            s += v[9]  - v[0]; o.y = s;
            s += v[10] - v[1]; o.z = s;
            s += v[11] - v[2]; o.w = s;
            float4 sv;
            sv.x = vert9(o.x); sv.y = vert9(o.y);
            sv.z = vert9(o.z); sv.w = vert9(o.w);
            if (wrt) {
                const int ch = sub ? (3 + t) : t;
                *(float4*)(shDst + ch * SH_CS + crow * SH_RS + 4 * g) = sv;
            }
        }
    };

    float q0[9], q1[9], q2[9], q3[9], q4[9];
    #pragma unroll
    for (int k = 0; k < 9; ++k) { q0[k]=0.f; q1[k]=0.f; q2[k]=0.f; q3[k]=0.f; q4[k]=0.f; }
    float r0=0.f, r1=0.f, r2=0.f, r3=0.f, r4=0.f;
    float acc = 0.f;

    // ---- prologue: WH(0) -> SH0 from slice z0; prefetch slice z0+1 ----
    const int z0 = dlo - 4;
    w_load(z0);
    if (z0 >= 0) wh_phase(SH0);            // z0 < DD always (dlo <= 140)
    w_load(z0 + 1);
    bar_lds_only();

    // ---- main: 36 phases, ONE barrier each ----
    #pragma unroll 1
    for (int gg = 0; gg < 4; ++gg) {
        #pragma unroll
        for (int ph = 0; ph < 9; ++ph) {
            const int j = 9 * gg + ph;
            const int z = dlo - 4 + j;               // slice consumed by F(j)
            const bool val = (z >= 0) && (z < DD);   // block-uniform
            float* shR = (j & 1) ? SH1 : SH0;
            float* shW = (j & 1) ? SH0 : SH1;

            // F(j): 5 LDS reads
            float w0=0.f, w1=0.f, w2=0.f, w3=0.f, w4=0.f;
            if (val) {
                const float* pF = shR + fy * SH_RS + fx;
                w0 = pF[0];
                w1 = pF[SH_CS];
                w2 = pF[2 * SH_CS];
                w3 = pF[3 * SH_CS];
                w4 = pF[4 * SH_CS];
            }

            // WH(j+1): regs -> SH[(j+1)&1]; refill pf for j+2
            if (j < ITERS - 1) {
                const int zh = z + 1;
                if (zh >= 0 && zh < DD) wh_phase(shW);
                w_load(z + 2);
            }

            // ring update + cc
            r0 += w0 - q0[ph]; q0[ph] = w0;
            r1 += w1 - q1[ph]; q1[ph] = w1;
            r2 += w2 - q2[ph]; q2[ph] = w2;
            r3 += w3 - q3[ph]; q3[ph] = w3;
            r4 += w4 - q4[ph]; q4[ph] = w4;

            if (j >= 8 && (dlo + j - 8) < DD) {   // last chunk overhangs to 167
                float cross = r4 - r0 * r1 * INV_WSUM;
                float iv    = r2 - r0 * r0 * INV_WSUM;
                float jv    = r3 - r1 * r1 * INV_WSUM;
                acc += cross * cross * __builtin_amdgcn_rcpf(iv * jv + EPS);
            }
            bar_lds_only();   // SH(j+1) visible to F(j+1); F done with shR
        }
    }

    // ---- block reduction -> one atomic (cold path: full __syncthreads ok) ----
    #pragma unroll
    for (int off = 32; off > 0; off >>= 1) acc += __shfl_down(acc, off, 64);
    if ((tid & 63) == 0) wred[tid >> 6] = acc;
    __syncthreads();
    if (tid == 0) {
        float t = 0.f;
        #pragma unroll
        for (int k = 0; k < NTHR / 64; ++k) t += wred[k];
        atomicAdd(out, t * (-1.0f / (float)NVOX));
    }
}

extern "C" void kernel_launch(void* const* d_in, const int* in_sizes, int n_in,
                              void* d_out, int out_size, void* d_ws, size_t ws_size,
                              hipStream_t stream) {
    const float* I = (const float*)d_in[0];
    const float* J = (const float*)d_in[1];
    float* out = (float*)d_out;

    hipMemsetAsync(d_out, 0, sizeof(float), stream);  // harness re-poisons d_out

    dim3 blk(NTHR, 1, 1);
    dim3 grd(WW / TW, HH / TH, (DD + DCH - 1) / DCH); // 7 x 24 x 6 = 1008 blocks
    ncc_fused<<<grd, blk, 0, stream>>>(I, J, out);
}

// Round 7
// 130.048 us; speedup vs baseline: 1.3340x; 1.3340x over previous
//
#include <hip/hip_runtime.h>

// NCC loss, win=9, (1,1,160,192,224) fp32 -> scalar. Fully fused, round 15
// (resubmit: R6 bench failed on container acquisition, not on the kernel).
// R14 post-mortem: LDS-BW theory refuted (3x less LDS -> 1.8x slower; DPP
// scan didn't fuse + half the lanes' work discarded). Standing model: dur ~
// issued-instructions on the CRITICAL wave (barrier-synced waves wait for the
// busiest one).
// R12 audit: role ranges OVERLAP. H = tid<160, W = tid>=128 -> tids 128-159
// (half of wave 2) ran H+W+F: wave 2 ~300 inst/phase vs 100 for waves 0/1.
// R15 = R12 with REBALANCED role mapping only (buffers/parity/barriers/DCH
// identical):
//   - W on ALL 256 threads: 2 threads per (row,group); tids 0-127 do
//     ch {I, J, I*I}, tids 128-255 do ch {J*J, I*J}. Both load the same 6
//     float4s (L1-served; HBM fetch unchanged).
//   - H spread over all 4 waves: wave w takes tasks w*40+lane, lane<40.
//   - F on all threads (unchanged).
// Per-wave issue ~175 inst/phase (was 300 on the critical wave).

#define DD 160
#define HH 192
#define WW 224
#define W4 56                 // WW/4
#define SLICE (HH * WW)
#define S4 (SLICE / 4)
#define NVOX (DD * SLICE)
#define TW 32
#define TH 8
#define DCH 28                // grid.z = 6 -> 1008 blocks
#define ITERS (DCH + 8)       // 36 = 4 * 9 (phase-static ring)
#define NTHR 256
#define SW_RS 36              // b128-aligned rows; 0-conflict measured (R5/R7)
#define SW_CS (16 * SW_RS)    // 576 floats: 16 rows = TH + 8
#define SH_SZ (TH * TW * 5)   // 1280 floats
#define EPS 1e-5f
#define INV_WSUM (1.0f / 729.0f)

// Barrier that orders LDS only: s_waitcnt imm 0xC07F = lgkmcnt(0), vmcnt(63),
// expcnt(7) -> in-flight GLOBAL loads stay in flight across the barrier.
__device__ __forceinline__ void bar_lds_only() {
    __asm__ volatile("" ::: "memory");
    __builtin_amdgcn_s_waitcnt(0xC07F);
    __builtin_amdgcn_s_barrier();
    __asm__ volatile("" ::: "memory");
}

__global__ __launch_bounds__(NTHR, 4) void ncc_fused(const float* __restrict__ I,
                                                     const float* __restrict__ J,
                                                     float* __restrict__ out) {
    __shared__ float SW0[5 * SW_CS], SW1[5 * SW_CS];   // 11.52 KB each
    __shared__ float SH0[SH_SZ], SH1[SH_SZ];           // 5.12 KB each
    __shared__ float wred[NTHR / 64];

    const int tid = threadIdx.x;
    const int tx = tid & 31, ty = tid >> 5;    // F mapping: 32 x 8
    const int wlo = blockIdx.x * TW;
    const int hlo = blockIdx.y * TH;
    const int dlo = blockIdx.z * DCH;

    // W mapping: ALL threads; 2 threads per (row, f4-group), split by channel.
    const int half = tid >> 7;                 // 0: ch {I,J,I*I}  1: {J*J,I*J}
    const int rg   = tid & 127;
    const int wr = rg >> 3, wc = rg & 7;       // 16 rows x 8 groups
    const int gh = hlo - 4 + wr;
    const bool hok = (gh >= 0) && (gh < HH);
    const int gf0 = (wlo >> 2) - 1 + wc;

    // H mapping: wave w takes tasks w*40 + lane (lane < 40); 160 tasks total.
    const int lane = tid & 63;
    const int htask = (tid >> 6) * 40 + lane;
    const bool hact = lane < 40;
    const int hcol = htask & 31, hch = htask >> 5;

    const float4* Iv = (const float4*)I;
    const float4* Jv = (const float4*)J;

    // prefetch registers: one slice-row of raw I/J (12 floats each)
    float pfa[12], pfb[12];

    auto w_load = [&](int z) {   // fill pfa/pfb for slice z (zeros if OOB)
        const bool zok = (z >= 0) && (z < DD) && hok;
        const int rowb = z * S4 + gh * W4;
        #pragma unroll
        for (int k = 0; k < 3; ++k) {
            const int f = gf0 + k;
            float4 a = make_float4(0.f, 0.f, 0.f, 0.f);
            float4 b = make_float4(0.f, 0.f, 0.f, 0.f);
            if (zok && f >= 0 && f < W4) { a = Iv[rowb + f]; b = Jv[rowb + f]; }
            pfa[4*k] = a.x; pfa[4*k+1] = a.y; pfa[4*k+2] = a.z; pfa[4*k+3] = a.w;
            pfb[4*k] = b.x; pfb[4*k+1] = b.y; pfb[4*k+2] = b.z; pfb[4*k+3] = b.w;
        }
    };

    // slide 9-tap W-sums for this thread's 2-3 channels -> dst
    auto w_compute = [&](float* dst) {
        float* wp = dst + wr * SW_RS + 4 * wc;
        #pragma unroll
        for (int t = 0; t < 3; ++t) {
            if (half && t == 2) break;         // wave-uniform: no wasted issue
            float v[12];
            #pragma unroll
            for (int k = 0; k < 12; ++k)
                v[k] = half ? ((t == 0) ? pfb[k] * pfb[k] : pfa[k] * pfb[k])
                            : ((t == 0) ? pfa[k]
                             : (t == 1) ? pfb[k]
                             :            pfa[k] * pfa[k]);
            float s = v[0];
            #pragma unroll
            for (int k = 1; k < 9; ++k) s += v[k];
            float4 o;
            o.x = s;
            s += v[9]  - v[0]; o.y = s;
            s += v[10] - v[1]; o.z = s;
            s += v[11] - v[2]; o.w = s;
            const int ch = half ? (3 + t) : t;
            *(float4*)(wp + ch * SW_CS) = o;   // b128, 16B-aligned
        }
    };

    auto h_phase = [&](const float* swSrc, float* shDst) {  // 9-tap H slide
        const float* p = swSrc + hch * SW_CS + hcol;
        float v[16];
        #pragma unroll
        for (int r = 0; r < 16; r += 2) {       // pairs -> ds_read2_b32
            const float* pr = p + r * SW_RS;
            v[r]     = pr[0];
            v[r + 1] = pr[SW_RS];
        }
        float s = v[0];
        #pragma unroll
        for (int r = 1; r < 9; ++r) s += v[r];
        float* o = shDst + hcol * 5 + hch;      // [row][col][ch]
        float prev = s;
        o[0] = s;
        #pragma unroll
        for (int r = 1; r < TH; ++r) {
            prev += v[r + 8] - v[r - 1];
            o[r * (TW * 5)] = prev;
        }
    };

    float q0[9], q1[9], q2[9], q3[9], q4[9];
    #pragma unroll
    for (int k = 0; k < 9; ++k) { q0[k]=0.f; q1[k]=0.f; q2[k]=0.f; q3[k]=0.f; q4[k]=0.f; }
    float r0=0.f, r1=0.f, r2=0.f, r3=0.f, r4=0.f;
    float acc = 0.f;

    // ---- prologue: W(0) -> SW0, prefetch slice 1 ----
    const int z0 = dlo - 4;
    w_load(z0);
    if (z0 >= 0) w_compute(SW0);        // z0 < DD always (dlo <= 140)
    w_load(z0 + 1);
    bar_lds_only();

    // ---- P0: H(0), W(1), prefetch slice 2 (no F yet) ----
    if (hact && z0 >= 0) h_phase(SW0, SH0);
    {
        const int z1 = z0 + 1;
        if (z1 >= 0 && z1 < DD) w_compute(SW1);
        w_load(z0 + 2);
    }

    // ---- main: 36 phases, ONE barrier each ----
    #pragma unroll 1
    for (int g = 0; g < 4; ++g) {
        #pragma unroll
        for (int ph = 0; ph < 9; ++ph) {
            const int j = 9 * g + ph;
            const int z = dlo - 4 + j;               // slice consumed by F(j)
            bar_lds_only();   // orders: H(j)->F(j), W(j+1)->H(j+1), bufs freed

            // F(j): issue LDS reads first
            const bool val = (z >= 0) && (z < DD);   // block-uniform
            float* shR = (j & 1) ? SH1 : SH0;
            float w0=0.f, w1=0.f, w2=0.f, w3=0.f, w4=0.f;
            if (val) {
                const float* pF = shR + (ty * TW + tx) * 5;
                w0 = pF[0]; w1 = pF[1]; w2 = pF[2]; w3 = pF[3]; w4 = pF[4];
            }

            // H(j+1): SW[(j+1)&1] -> SH[(j+1)&1]   (guard j+1 <= ITERS-1)
            if ((g < 3 || ph < 8) && hact) {
                const int zh = z + 1;
                if (zh >= 0 && zh < DD)
                    h_phase((j & 1) ? SW0 : SW1, (j & 1) ? SH0 : SH1);
            }

            // W(j+2): pf regs -> SW[(j+2)&1]; refill pf   (guard j+2 <= ITERS-1)
            if (g < 3 || ph < 7) {
                const int zw = z + 2;
                if (zw >= 0 && zw < DD) w_compute((j & 1) ? SW1 : SW0);
                w_load(z + 3);
            }

            // ring update + cc
            r0 += w0 - q0[ph]; q0[ph] = w0;
            r1 += w1 - q1[ph]; q1[ph] = w1;
            r2 += w2 - q2[ph]; q2[ph] = w2;
            r3 += w3 - q3[ph]; q3[ph] = w3;
            r4 += w4 - q4[ph]; q4[ph] = w4;

            if (j >= 8 && (dlo + j - 8) < DD) {   // last chunk overhangs to 167
                float cross = r4 - r0 * r1 * INV_WSUM;
                float iv    = r2 - r0 * r0 * INV_WSUM;
                float jv    = r3 - r1 * r1 * INV_WSUM;
                acc += cross * cross * __builtin_amdgcn_rcpf(iv * jv + EPS);
            }
        }
    }

    // ---- block reduction -> one atomic (cold path: full __syncthreads ok) ----
    #pragma unroll
    for (int off = 32; off > 0; off >>= 1) acc += __shfl_down(acc, off, 64);
    if ((tid & 63) == 0) wred[tid >> 6] = acc;
    __syncthreads();
    if (tid == 0) {
        float t = 0.f;
        #pragma unroll
        for (int k = 0; k < NTHR / 64; ++k) t += wred[k];
        atomicAdd(out, t * (-1.0f / (float)NVOX));
    }
}

extern "C" void kernel_launch(void* const* d_in, const int* in_sizes, int n_in,
                              void* d_out, int out_size, void* d_ws, size_t ws_size,
                              hipStream_t stream) {
    const float* I = (const float*)d_in[0];
    const float* J = (const float*)d_in[1];
    float* out = (float*)d_out;

    hipMemsetAsync(d_out, 0, sizeof(float), stream);  // harness re-poisons d_out

    dim3 blk(NTHR, 1, 1);
    dim3 grd(WW / TW, HH / TH, (DD + DCH - 1) / DCH); // 7 x 24 x 6 = 1008 blocks
    ncc_fused<<<grd, blk, 0, stream>>>(I, J, out);
}